// Round 5
// baseline (108.675 us; speedup 1.0000x reference)
//
#include <hip/hip_runtime.h>
#include <math.h>

#define B_   512
#define W_   30
#define R_   512
#define D_   128
#define NK_  21
#define QSTRIDE 132   // 128 + 4 pad: conflict-free norm phase; dot phase uses broadcast anyway

__global__ __launch_bounds__(512) void knrm_kernel(
    const int* __restrict__ query,      // [B,W] int32
    const int* __restrict__ doc,        // [B,R] int32
    const float* __restrict__ emb,      // [V,D] f32
    const float* __restrict__ w1, const float* __restrict__ b1,
    const float* __restrict__ w2, const float* __restrict__ b2,
    const float* __restrict__ w3, const float* __restrict__ b3,
    float* __restrict__ out)            // [B]
{
    const int b   = blockIdx.x;
    const int tid = threadIdx.x;

    __shared__ float qs[W_ * QSTRIDE];
    __shared__ float qinv[W_];
    __shared__ float wred[8][NK_];
    __shared__ float klds[NK_];
    __shared__ float h1lds[128];

    // ---- stage raw query embeddings into LDS (coalesced) ----
    for (int idx = tid; idx < W_ * D_; idx += 512) {
        int w = idx >> 7, k = idx & 127;
        int qi = query[b * W_ + w];
        qs[w * QSTRIDE + k] = emb[(size_t)qi * D_ + k];
    }
    __syncthreads();

    // ---- per-row inverse norms (30 rows x 16 lanes each) ----
    if (tid < W_ * 16) {
        int row = tid >> 4, j = tid & 15;
        float ss = 0.f;
        #pragma unroll
        for (int k = 0; k < D_; k += 16) {
            float v = qs[row * QSTRIDE + k + j];
            ss = fmaf(v, v, ss);
        }
        #pragma unroll
        for (int off = 8; off >= 1; off >>= 1) ss += __shfl_xor(ss, off, 16);
        if (j == 0) qinv[row] = 1.0f / fmaxf(sqrtf(ss), 1e-12f);
    }
    __syncthreads();

    // ---- main: each thread owns one document row r = tid ----
    const int r    = tid;
    const int didx = doc[b * R_ + r];
    const float4* __restrict__ drow = (const float4*)(emb + (size_t)didx * D_);

    float acc[W_];
    #pragma unroll
    for (int w = 0; w < W_; ++w) acc[w] = 0.f;
    float nsq = 0.f;

    float4 dv = drow[0];
    for (int c = 0; c < D_ / 4; ++c) {
        float4 dnx = drow[(c + 1) & 31];      // prefetch next chunk (wraps harmlessly)
        nsq = fmaf(dv.x, dv.x, fmaf(dv.y, dv.y, fmaf(dv.z, dv.z, fmaf(dv.w, dv.w, nsq))));
        const float* qc = qs + c * 4;
        #pragma unroll
        for (int w = 0; w < W_; ++w) {
            float4 qv = *(const float4*)(qc + w * QSTRIDE);   // uniform addr -> LDS broadcast
            acc[w] = fmaf(qv.x, dv.x, fmaf(qv.y, dv.y, fmaf(qv.z, dv.z, fmaf(qv.w, dv.w, acc[w]))));
        }
        dv = dnx;
    }

    const float invd = 1.0f / fmaxf(sqrtf(nsq), 1e-12f);

    // ---- 21 Gaussian soft-histogram bins (base-2 exponent, constants pre-folded) ----
    // c_wide = -0.5/sigma^2 * log2(e), sigma=0.1 ; c_exact for sigma=0.001
    const float CW = -72.134752f;
    const float CE = -721347.52f;

    float kacc[NK_];
    #pragma unroll
    for (int i = 0; i < NK_; ++i) kacc[i] = 0.f;

    #pragma unroll
    for (int w = 0; w < W_; ++w) {
        float m = acc[w] * qinv[w] * invd;
        #pragma unroll
        for (int i = 0; i < 20; ++i) {
            const float mu = (float)(1.0 / (NK_ - 1) + 2.0 * (double)i / (NK_ - 1) - 1.0);
            float t = m - mu;
            kacc[i] += exp2f(CW * t * t);
        }
        float y = m - 1.0f;
        kacc[20] += exp2f(CE * y * y);
    }

    // ---- block reduction of the 21 accumulators ----
    const int wid = tid >> 6, lane = tid & 63;
    #pragma unroll
    for (int i = 0; i < NK_; ++i) {
        float v = kacc[i];
        #pragma unroll
        for (int off = 32; off >= 1; off >>= 1) v += __shfl_xor(v, off, 64);
        if (lane == 0) wred[wid][i] = v;
    }
    __syncthreads();
    if (tid < NK_) {
        float s = 0.f;
        #pragma unroll
        for (int ww = 0; ww < 8; ++ww) s += wred[ww][tid];
        klds[tid] = log1pf(s);
    }
    __syncthreads();

    // ---- tiny MLP: 21 -> 128 -> 64 -> 1, fused in-block ----
    if (tid < 128) {
        float h = b1[tid];
        #pragma unroll
        for (int i = 0; i < NK_; ++i) h = fmaf(klds[i], w1[i * 128 + tid], h);
        h1lds[tid] = fmaxf(h, 0.f);
    }
    __syncthreads();
    if (tid < 64) {
        float h = b2[tid];
        #pragma unroll 8
        for (int i = 0; i < 128; ++i) h = fmaf(h1lds[i], w2[i * 64 + tid], h);
        float p = fmaxf(h, 0.f) * w3[tid];
        #pragma unroll
        for (int off = 32; off >= 1; off >>= 1) p += __shfl_xor(p, off, 64);
        if (tid == 0) out[b] = p + b3[0];
    }
}

extern "C" void kernel_launch(void* const* d_in, const int* in_sizes, int n_in,
                              void* d_out, int out_size, void* d_ws, size_t ws_size,
                              hipStream_t stream) {
    const int*   query = (const int*)d_in[0];
    const int*   doc   = (const int*)d_in[1];
    const float* emb   = (const float*)d_in[2];
    const float* w1    = (const float*)d_in[3];
    const float* b1    = (const float*)d_in[4];
    const float* w2    = (const float*)d_in[5];
    const float* b2    = (const float*)d_in[6];
    const float* w3    = (const float*)d_in[7];
    const float* b3    = (const float*)d_in[8];
    float* outp = (float*)d_out;

    knrm_kernel<<<dim3(B_), dim3(512), 0, stream>>>(query, doc, emb,
                                                    w1, b1, w2, b2, w3, b3, outp);
}

// Round 9
// 74.349 us; speedup vs baseline: 1.4617x; 1.4617x over previous
//
#include <hip/hip_runtime.h>
#include <math.h>

#define B_   512
#define W_   30
#define R_   512
#define D_   128
#define NK_  21
#define QSTRIDE 132   // fp32 fallback kernel: 128 + 4 pad

typedef __attribute__((ext_vector_type(8))) short  bf16x8;
typedef __attribute__((ext_vector_type(4))) float  f32x4;

__device__ __forceinline__ unsigned short f2bf(float f) {
    union { float f; unsigned int u; } v; v.f = f;
    unsigned int u = v.u;
    return (unsigned short)((u + 0x7fffu + ((u >> 16) & 1u)) >> 16);  // RTNE
}

// ---------------- kernel 1: normalize emb table -> bf16 table in d_ws ----------------
__global__ __launch_bounds__(256) void norm_table_kernel(
    const float* __restrict__ emb, unsigned short* __restrict__ tbl, int V)
{
    const int t   = threadIdx.x;
    const int row = blockIdx.x * 16 + (t >> 4);
    const int j   = t & 15;                      // 16 lanes per row, 8 f32 each
    if (row >= V) return;

    const float4* src = (const float4*)(emb + (size_t)row * D_ + j * 8);
    float4 a = src[0], b = src[1];
    float ss = a.x*a.x + a.y*a.y + a.z*a.z + a.w*a.w
             + b.x*b.x + b.y*b.y + b.z*b.z + b.w*b.w;
    #pragma unroll
    for (int off = 8; off >= 1; off >>= 1) ss += __shfl_xor(ss, off, 16);
    const float inv = 1.0f / fmaxf(sqrtf(ss), 1e-12f);

    unsigned short o[8];
    o[0] = f2bf(a.x*inv); o[1] = f2bf(a.y*inv); o[2] = f2bf(a.z*inv); o[3] = f2bf(a.w*inv);
    o[4] = f2bf(b.x*inv); o[5] = f2bf(b.y*inv); o[6] = f2bf(b.z*inv); o[7] = f2bf(b.w*inv);
    *(uint4*)(tbl + (size_t)row * D_ + j * 8) = *(const uint4*)o;
}

// ---------------- kernel 2: MFMA cosine matrix + bins + MLP ----------------
#define QROWS 32
#define QST   136   // ushort stride per row (272 B): breaks 16-row same-bank pattern

__global__ __launch_bounds__(512) void knrm_mfma_kernel(
    const int* __restrict__ query, const int* __restrict__ doc,
    const unsigned short* __restrict__ tbl,   // [V][128] normalized bf16
    const float* __restrict__ w1, const float* __restrict__ b1,
    const float* __restrict__ w2, const float* __restrict__ b2,
    const float* __restrict__ w3, const float* __restrict__ b3,
    float* __restrict__ out)
{
    const int b    = blockIdx.x;
    const int tid  = threadIdx.x;
    const int lane = tid & 63;
    const int wid  = tid >> 6;          // 8 waves
    const int l15  = lane & 15;
    const int lhi  = lane >> 4;

    __shared__ unsigned short qlds[QROWS * QST];
    __shared__ float wred[8][NK_];
    __shared__ float klds[NK_];
    __shared__ float h1lds[128];

    // ---- gather pre-normalized q-hat rows (bf16) into LDS; pad rows 30,31 with 0 ----
    {
        int w = tid >> 4, j = tid & 15;
        uint4 v = make_uint4(0, 0, 0, 0);
        if (w < W_) {
            int qi = query[b * W_ + w];
            v = *(const uint4*)(tbl + (size_t)qi * D_ + j * 8);
        }
        *(uint4*)(&qlds[w * QST + j * 8]) = v;
    }
    __syncthreads();

    // ---- B fragments: q-hat rows, 2 col-tiles x 4 k-steps, 8 bf16/lane each ----
    bf16x8 bq[2][4];
    #pragma unroll
    for (int tc = 0; tc < 2; ++tc)
        #pragma unroll
        for (int kk = 0; kk < 4; ++kk)
            bq[tc][kk] = *(const bf16x8*)&qlds[(tc * 16 + l15) * QST + kk * 32 + lhi * 8];

    // ---- MFMA: wave owns 64 doc rows; A fragments straight from global bf16 table ----
    f32x4 acc[4][2];
    #pragma unroll
    for (int tr = 0; tr < 4; ++tr) { acc[tr][0] = (f32x4)0.0f; acc[tr][1] = (f32x4)0.0f; }

    #pragma unroll
    for (int tr = 0; tr < 4; ++tr) {
        const int r  = wid * 64 + tr * 16 + l15;
        const int di = doc[b * R_ + r];
        const unsigned short* base = tbl + (size_t)di * D_ + lhi * 8;
        #pragma unroll
        for (int kk = 0; kk < 4; ++kk) {
            bf16x8 a = *(const bf16x8*)(base + kk * 32);
            acc[tr][0] = __builtin_amdgcn_mfma_f32_16x16x32_bf16(a, bq[0][kk], acc[tr][0], 0, 0, 0);
            acc[tr][1] = __builtin_amdgcn_mfma_f32_16x16x32_bf16(a, bq[1][kk], acc[tr][1], 0, 0, 0);
        }
    }

    // ---- bins: each lane processes its 32 M values (col = w = tc*16 + l15) ----
    const float CW = -72.134752f;     // -0.5/0.1^2 * log2(e)
    const float CE = -721347.52f;     // -0.5/0.001^2 * log2(e)
    const float msk1 = (l15 < 14) ? 1.0f : 0.0f;   // mask w>=30 in col-tile 1

    float kacc[NK_];
    #pragma unroll
    for (int i = 0; i < NK_; ++i) kacc[i] = 0.f;

    #pragma unroll
    for (int tr = 0; tr < 4; ++tr) {
        #pragma unroll
        for (int p = 0; p < 4; ++p) {
            {   // col-tile 0: w = l15 < 16, always valid
                float m = acc[tr][0][p];
                #pragma unroll
                for (int i = 0; i < 20; ++i) {
                    const float mu = (float)(1.0 / (NK_ - 1) + 2.0 * (double)i / (NK_ - 1) - 1.0);
                    float t = m - mu;
                    kacc[i] += exp2f(CW * t * t);
                }
                float y = m - 1.0f;
                kacc[20] += exp2f(CE * y * y);
            }
            {   // col-tile 1: w = 16 + l15, mask w >= 30
                float m = acc[tr][1][p];
                #pragma unroll
                for (int i = 0; i < 20; ++i) {
                    const float mu = (float)(1.0 / (NK_ - 1) + 2.0 * (double)i / (NK_ - 1) - 1.0);
                    float t = m - mu;
                    kacc[i] = fmaf(msk1, exp2f(CW * t * t), kacc[i]);
                }
                float y = m - 1.0f;
                kacc[20] = fmaf(msk1, exp2f(CE * y * y), kacc[20]);
            }
        }
    }

    // ---- block reduction of 21 accumulators ----
    #pragma unroll
    for (int i = 0; i < NK_; ++i) {
        float v = kacc[i];
        #pragma unroll
        for (int off = 32; off >= 1; off >>= 1) v += __shfl_xor(v, off, 64);
        if (lane == 0) wred[wid][i] = v;
    }
    __syncthreads();
    if (tid < NK_) {
        float s = 0.f;
        #pragma unroll
        for (int ww = 0; ww < 8; ++ww) s += wred[ww][tid];
        klds[tid] = log1pf(s);
    }
    __syncthreads();

    // ---- MLP 21 -> 128 -> 64 -> 1 ----
    if (tid < 128) {
        float h = b1[tid];
        #pragma unroll
        for (int i = 0; i < NK_; ++i) h = fmaf(klds[i], w1[i * 128 + tid], h);
        h1lds[tid] = fmaxf(h, 0.f);
    }
    __syncthreads();
    if (tid < 64) {
        float h = b2[tid];
        #pragma unroll 8
        for (int i = 0; i < 128; ++i) h = fmaf(h1lds[i], w2[i * 64 + tid], h);
        float p = fmaxf(h, 0.f) * w3[tid];
        #pragma unroll
        for (int off = 32; off >= 1; off >>= 1) p += __shfl_xor(p, off, 64);
        if (tid == 0) out[b] = p + b3[0];
    }
}

// ---------------- fp32 fallback (round-5 kernel, exact) ----------------
__global__ __launch_bounds__(512) void knrm_kernel(
    const int* __restrict__ query, const int* __restrict__ doc,
    const float* __restrict__ emb,
    const float* __restrict__ w1, const float* __restrict__ b1,
    const float* __restrict__ w2, const float* __restrict__ b2,
    const float* __restrict__ w3, const float* __restrict__ b3,
    float* __restrict__ out)
{
    const int b   = blockIdx.x;
    const int tid = threadIdx.x;

    __shared__ float qs[W_ * QSTRIDE];
    __shared__ float qinv[W_];
    __shared__ float wred[8][NK_];
    __shared__ float klds[NK_];
    __shared__ float h1lds[128];

    for (int idx = tid; idx < W_ * D_; idx += 512) {
        int w = idx >> 7, k = idx & 127;
        int qi = query[b * W_ + w];
        qs[w * QSTRIDE + k] = emb[(size_t)qi * D_ + k];
    }
    __syncthreads();

    if (tid < W_ * 16) {
        int row = tid >> 4, j = tid & 15;
        float ss = 0.f;
        #pragma unroll
        for (int k = 0; k < D_; k += 16) {
            float v = qs[row * QSTRIDE + k + j];
            ss = fmaf(v, v, ss);
        }
        #pragma unroll
        for (int off = 8; off >= 1; off >>= 1) ss += __shfl_xor(ss, off, 16);
        if (j == 0) qinv[row] = 1.0f / fmaxf(sqrtf(ss), 1e-12f);
    }
    __syncthreads();

    const int didx = doc[b * R_ + tid];
    const float4* __restrict__ drow = (const float4*)(emb + (size_t)didx * D_);

    float acc[W_];
    #pragma unroll
    for (int w = 0; w < W_; ++w) acc[w] = 0.f;
    float nsq = 0.f;

    float4 dv = drow[0];
    for (int c = 0; c < D_ / 4; ++c) {
        float4 dnx = drow[(c + 1) & 31];
        nsq = fmaf(dv.x, dv.x, fmaf(dv.y, dv.y, fmaf(dv.z, dv.z, fmaf(dv.w, dv.w, nsq))));
        const float* qc = qs + c * 4;
        #pragma unroll
        for (int w = 0; w < W_; ++w) {
            float4 qv = *(const float4*)(qc + w * QSTRIDE);
            acc[w] = fmaf(qv.x, dv.x, fmaf(qv.y, dv.y, fmaf(qv.z, dv.z, fmaf(qv.w, dv.w, acc[w]))));
        }
        dv = dnx;
    }
    const float invd = 1.0f / fmaxf(sqrtf(nsq), 1e-12f);

    const float CW = -72.134752f;
    const float CE = -721347.52f;
    float kacc[NK_];
    #pragma unroll
    for (int i = 0; i < NK_; ++i) kacc[i] = 0.f;

    #pragma unroll
    for (int w = 0; w < W_; ++w) {
        float m = acc[w] * qinv[w] * invd;
        #pragma unroll
        for (int i = 0; i < 20; ++i) {
            const float mu = (float)(1.0 / (NK_ - 1) + 2.0 * (double)i / (NK_ - 1) - 1.0);
            float t = m - mu;
            kacc[i] += exp2f(CW * t * t);
        }
        float y = m - 1.0f;
        kacc[20] += exp2f(CE * y * y);
    }

    const int wid = tid >> 6, lane = tid & 63;
    #pragma unroll
    for (int i = 0; i < NK_; ++i) {
        float v = kacc[i];
        #pragma unroll
        for (int off = 32; off >= 1; off >>= 1) v += __shfl_xor(v, off, 64);
        if (lane == 0) wred[wid][i] = v;
    }
    __syncthreads();
    if (tid < NK_) {
        float s = 0.f;
        #pragma unroll
        for (int ww = 0; ww < 8; ++ww) s += wred[ww][tid];
        klds[tid] = log1pf(s);
    }
    __syncthreads();

    if (tid < 128) {
        float h = b1[tid];
        #pragma unroll
        for (int i = 0; i < NK_; ++i) h = fmaf(klds[i], w1[i * 128 + tid], h);
        h1lds[tid] = fmaxf(h, 0.f);
    }
    __syncthreads();
    if (tid < 64) {
        float h = b2[tid];
        #pragma unroll 8
        for (int i = 0; i < 128; ++i) h = fmaf(h1lds[i], w2[i * 64 + tid], h);
        float p = fmaxf(h, 0.f) * w3[tid];
        #pragma unroll
        for (int off = 32; off >= 1; off >>= 1) p += __shfl_xor(p, off, 64);
        if (tid == 0) out[b] = p + b3[0];
    }
}

extern "C" void kernel_launch(void* const* d_in, const int* in_sizes, int n_in,
                              void* d_out, int out_size, void* d_ws, size_t ws_size,
                              hipStream_t stream) {
    const int*   query = (const int*)d_in[0];
    const int*   doc   = (const int*)d_in[1];
    const float* emb   = (const float*)d_in[2];
    const float* w1    = (const float*)d_in[3];
    const float* b1    = (const float*)d_in[4];
    const float* w2    = (const float*)d_in[5];
    const float* b2    = (const float*)d_in[6];
    const float* w3    = (const float*)d_in[7];
    const float* b3    = (const float*)d_in[8];
    float* outp = (float*)d_out;

    const int V = in_sizes[2] / D_;
    const size_t need = (size_t)V * D_ * sizeof(unsigned short);

    if (ws_size >= need) {
        unsigned short* tbl = (unsigned short*)d_ws;
        norm_table_kernel<<<dim3((V + 15) / 16), dim3(256), 0, stream>>>(emb, tbl, V);
        knrm_mfma_kernel<<<dim3(B_), dim3(512), 0, stream>>>(query, doc, tbl,
                                                             w1, b1, w2, b2, w3, b3, outp);
    } else {
        knrm_kernel<<<dim3(B_), dim3(512), 0, stream>>>(query, doc, emb,
                                                        w1, b1, w2, b2, w3, b3, outp);
    }
}

// Round 10
// 58.386 us; speedup vs baseline: 1.8613x; 1.2734x over previous
//
#include <hip/hip_runtime.h>
#include <math.h>

#define B_   512
#define W_   30
#define R_   512
#define D_   128
#define NK_  21
#define QSTRIDE 132   // fp32 fallback kernel: 128 + 4 pad

typedef __attribute__((ext_vector_type(8))) short  bf16x8;
typedef __attribute__((ext_vector_type(4))) float  f32x4;
typedef __attribute__((ext_vector_type(2))) float  f32x2;

__device__ __forceinline__ unsigned short f2bf(float f) {
    union { float f; unsigned int u; } v; v.f = f;
    unsigned int u = v.u;
    return (unsigned short)((u + 0x7fffu + ((u >> 16) & 1u)) >> 16);  // RTNE
}

__device__ __forceinline__ float fast_exp2(float x) {
#if __has_builtin(__builtin_amdgcn_exp2f)
    return __builtin_amdgcn_exp2f(x);
#else
    float r; asm volatile("v_exp_f32 %0, %1" : "=v"(r) : "v"(x)); return r;
#endif
}

// ---------------- kernel 1: normalize emb table -> bf16 table in d_ws ----------------
__global__ __launch_bounds__(256) void norm_table_kernel(
    const float* __restrict__ emb, unsigned short* __restrict__ tbl, int V)
{
    const int t   = threadIdx.x;
    const int row = blockIdx.x * 16 + (t >> 4);
    const int j   = t & 15;                      // 16 lanes per row, 8 f32 each
    if (row >= V) return;

    const float4* src = (const float4*)(emb + (size_t)row * D_ + j * 8);
    float4 a = src[0], b = src[1];
    float ss = a.x*a.x + a.y*a.y + a.z*a.z + a.w*a.w
             + b.x*b.x + b.y*b.y + b.z*b.z + b.w*b.w;
    #pragma unroll
    for (int off = 8; off >= 1; off >>= 1) ss += __shfl_xor(ss, off, 16);
    const float inv = 1.0f / fmaxf(sqrtf(ss), 1e-12f);

    unsigned short o[8];
    o[0] = f2bf(a.x*inv); o[1] = f2bf(a.y*inv); o[2] = f2bf(a.z*inv); o[3] = f2bf(a.w*inv);
    o[4] = f2bf(b.x*inv); o[5] = f2bf(b.y*inv); o[6] = f2bf(b.z*inv); o[7] = f2bf(b.w*inv);
    *(uint4*)(tbl + (size_t)row * D_ + j * 8) = *(const uint4*)o;
}

// ---------------- kernel 2: MFMA cosine matrix + bins + MLP ----------------
#define QROWS 32
#define QST   136   // ushort stride per row (272 B): breaks 16-row same-bank pattern

__global__ __launch_bounds__(512) void knrm_mfma_kernel(
    const int* __restrict__ query, const int* __restrict__ doc,
    const unsigned short* __restrict__ tbl,   // [V][128] normalized bf16
    const float* __restrict__ w1, const float* __restrict__ b1,
    const float* __restrict__ w2, const float* __restrict__ b2,
    const float* __restrict__ w3, const float* __restrict__ b3,
    float* __restrict__ out)
{
    const int b    = blockIdx.x;
    const int tid  = threadIdx.x;
    const int lane = tid & 63;
    const int wid  = tid >> 6;          // 8 waves
    const int l15  = lane & 15;
    const int lhi  = lane >> 4;

    __shared__ unsigned short qlds[QROWS * QST];
    __shared__ float wred[8][NK_];
    __shared__ float klds[NK_];
    __shared__ float h1lds[128];

    // ---- gather pre-normalized q-hat rows (bf16) into LDS; pad rows 30,31 with 0 ----
    {
        int w = tid >> 4, j = tid & 15;
        uint4 v = make_uint4(0, 0, 0, 0);
        if (w < W_) {
            int qi = query[b * W_ + w];
            v = *(const uint4*)(tbl + (size_t)qi * D_ + j * 8);
        }
        *(uint4*)(&qlds[w * QST + j * 8]) = v;
    }
    __syncthreads();

    // ---- B fragments: q-hat rows, 2 col-tiles x 4 k-steps, 8 bf16/lane each ----
    bf16x8 bq[2][4];
    #pragma unroll
    for (int tc = 0; tc < 2; ++tc)
        #pragma unroll
        for (int kk = 0; kk < 4; ++kk)
            bq[tc][kk] = *(const bf16x8*)&qlds[(tc * 16 + l15) * QST + kk * 32 + lhi * 8];

    // ---- MFMA: wave owns 64 doc rows; A fragments straight from global bf16 table ----
    f32x4 acc[4][2];
    #pragma unroll
    for (int tr = 0; tr < 4; ++tr) { acc[tr][0] = (f32x4)0.0f; acc[tr][1] = (f32x4)0.0f; }

    #pragma unroll
    for (int tr = 0; tr < 4; ++tr) {
        const int r  = wid * 64 + tr * 16 + l15;
        const int di = doc[b * R_ + r];
        const unsigned short* base = tbl + (size_t)di * D_ + lhi * 8;
        #pragma unroll
        for (int kk = 0; kk < 4; ++kk) {
            bf16x8 a = *(const bf16x8*)(base + kk * 32);
            acc[tr][0] = __builtin_amdgcn_mfma_f32_16x16x32_bf16(a, bq[0][kk], acc[tr][0], 0, 0, 0);
            acc[tr][1] = __builtin_amdgcn_mfma_f32_16x16x32_bf16(a, bq[1][kk], acc[tr][1], 0, 0, 0);
        }
    }

    // ---- bins: pairs (tile0, tile1); exponent recurrence + raw v_exp_f32 ----
    // e_i = CW*(m-mu_i)^2 ; e_{i+1} = e_i + d_i ; d_{i+1} = d_i + 2*CW*delta^2
    // CW = -0.5/0.1^2*log2(e); masked tile-1 lanes use m=3.0 -> all terms exp2(<=-303)=0
    const float CW = -72.134752f;
    const float CE = -721347.52f;     // exact bin, sigma=0.001

    f32x2 kacc2[NK_];
    #pragma unroll
    for (int i = 0; i < NK_; ++i) kacc2[i] = (f32x2)0.0f;

    #pragma unroll
    for (int tr = 0; tr < 4; ++tr) {
        #pragma unroll
        for (int p = 0; p < 4; ++p) {
            f32x2 mm;
            mm.x = acc[tr][0][p];                            // w = l15 (always valid)
            mm.y = (l15 < 14) ? acc[tr][1][p] : 3.0f;        // w = 16+l15, mask w>=30
            f32x2 t = mm + 0.95f;                            // m - mu0, mu0 = -0.95
            f32x2 e = (CW * t) * t;
            f32x2 d = 14.4269504f * t - 0.72134752f;         // CW*d^2 - 2*CW*delta*t
            #pragma unroll
            for (int i = 0; i < 20; ++i) {
                f32x2 T;
                T.x = fast_exp2(e.x);
                T.y = fast_exp2(e.y);
                kacc2[i] += T;
                e += d;
                d += -1.44269504f;                           // 2*CW*delta^2
            }
            f32x2 y = mm - 1.0f;
            f32x2 a20 = (CE * y) * y;
            f32x2 T20;
            T20.x = fast_exp2(a20.x);
            T20.y = fast_exp2(a20.y);
            kacc2[20] += T20;
        }
    }

    // ---- block reduction of 21 accumulators ----
    #pragma unroll
    for (int i = 0; i < NK_; ++i) {
        float v = kacc2[i].x + kacc2[i].y;
        #pragma unroll
        for (int off = 32; off >= 1; off >>= 1) v += __shfl_xor(v, off, 64);
        if (lane == 0) wred[wid][i] = v;
    }
    __syncthreads();
    if (tid < NK_) {
        float s = 0.f;
        #pragma unroll
        for (int ww = 0; ww < 8; ++ww) s += wred[ww][tid];
        klds[tid] = log1pf(s);
    }
    __syncthreads();

    // ---- MLP 21 -> 128 -> 64 -> 1 ----
    if (tid < 128) {
        float h = b1[tid];
        #pragma unroll
        for (int i = 0; i < NK_; ++i) h = fmaf(klds[i], w1[i * 128 + tid], h);
        h1lds[tid] = fmaxf(h, 0.f);
    }
    __syncthreads();
    if (tid < 64) {
        float h = b2[tid];
        #pragma unroll 8
        for (int i = 0; i < 128; ++i) h = fmaf(h1lds[i], w2[i * 64 + tid], h);
        float p = fmaxf(h, 0.f) * w3[tid];
        #pragma unroll
        for (int off = 32; off >= 1; off >>= 1) p += __shfl_xor(p, off, 64);
        if (tid == 0) out[b] = p + b3[0];
    }
}

// ---------------- fp32 fallback (round-5 kernel, exact) ----------------
__global__ __launch_bounds__(512) void knrm_kernel(
    const int* __restrict__ query, const int* __restrict__ doc,
    const float* __restrict__ emb,
    const float* __restrict__ w1, const float* __restrict__ b1,
    const float* __restrict__ w2, const float* __restrict__ b2,
    const float* __restrict__ w3, const float* __restrict__ b3,
    float* __restrict__ out)
{
    const int b   = blockIdx.x;
    const int tid = threadIdx.x;

    __shared__ float qs[W_ * QSTRIDE];
    __shared__ float qinv[W_];
    __shared__ float wred[8][NK_];
    __shared__ float klds[NK_];
    __shared__ float h1lds[128];

    for (int idx = tid; idx < W_ * D_; idx += 512) {
        int w = idx >> 7, k = idx & 127;
        int qi = query[b * W_ + w];
        qs[w * QSTRIDE + k] = emb[(size_t)qi * D_ + k];
    }
    __syncthreads();

    if (tid < W_ * 16) {
        int row = tid >> 4, j = tid & 15;
        float ss = 0.f;
        #pragma unroll
        for (int k = 0; k < D_; k += 16) {
            float v = qs[row * QSTRIDE + k + j];
            ss = fmaf(v, v, ss);
        }
        #pragma unroll
        for (int off = 8; off >= 1; off >>= 1) ss += __shfl_xor(ss, off, 16);
        if (j == 0) qinv[row] = 1.0f / fmaxf(sqrtf(ss), 1e-12f);
    }
    __syncthreads();

    const int didx = doc[b * R_ + tid];
    const float4* __restrict__ drow = (const float4*)(emb + (size_t)didx * D_);

    float acc[W_];
    #pragma unroll
    for (int w = 0; w < W_; ++w) acc[w] = 0.f;
    float nsq = 0.f;

    float4 dv = drow[0];
    for (int c = 0; c < D_ / 4; ++c) {
        float4 dnx = drow[(c + 1) & 31];
        nsq = fmaf(dv.x, dv.x, fmaf(dv.y, dv.y, fmaf(dv.z, dv.z, fmaf(dv.w, dv.w, nsq))));
        const float* qc = qs + c * 4;
        #pragma unroll
        for (int w = 0; w < W_; ++w) {
            float4 qv = *(const float4*)(qc + w * QSTRIDE);
            acc[w] = fmaf(qv.x, dv.x, fmaf(qv.y, dv.y, fmaf(qv.z, dv.z, fmaf(qv.w, dv.w, acc[w]))));
        }
        dv = dnx;
    }
    const float invd = 1.0f / fmaxf(sqrtf(nsq), 1e-12f);

    const float CW = -72.134752f;
    const float CE = -721347.52f;
    float kacc[NK_];
    #pragma unroll
    for (int i = 0; i < NK_; ++i) kacc[i] = 0.f;

    #pragma unroll
    for (int w = 0; w < W_; ++w) {
        float m = acc[w] * qinv[w] * invd;
        #pragma unroll
        for (int i = 0; i < 20; ++i) {
            const float mu = (float)(1.0 / (NK_ - 1) + 2.0 * (double)i / (NK_ - 1) - 1.0);
            float t = m - mu;
            kacc[i] += exp2f(CW * t * t);
        }
        float y = m - 1.0f;
        kacc[20] += exp2f(CE * y * y);
    }

    const int wid = tid >> 6, lane = tid & 63;
    #pragma unroll
    for (int i = 0; i < NK_; ++i) {
        float v = kacc[i];
        #pragma unroll
        for (int off = 32; off >= 1; off >>= 1) v += __shfl_xor(v, off, 64);
        if (lane == 0) wred[wid][i] = v;
    }
    __syncthreads();
    if (tid < NK_) {
        float s = 0.f;
        #pragma unroll
        for (int ww = 0; ww < 8; ++ww) s += wred[ww][tid];
        klds[tid] = log1pf(s);
    }
    __syncthreads();

    if (tid < 128) {
        float h = b1[tid];
        #pragma unroll
        for (int i = 0; i < NK_; ++i) h = fmaf(klds[i], w1[i * 128 + tid], h);
        h1lds[tid] = fmaxf(h, 0.f);
    }
    __syncthreads();
    if (tid < 64) {
        float h = b2[tid];
        #pragma unroll 8
        for (int i = 0; i < 128; ++i) h = fmaf(h1lds[i], w2[i * 64 + tid], h);
        float p = fmaxf(h, 0.f) * w3[tid];
        #pragma unroll
        for (int off = 32; off >= 1; off >>= 1) p += __shfl_xor(p, off, 64);
        if (tid == 0) out[b] = p + b3[0];
    }
}

extern "C" void kernel_launch(void* const* d_in, const int* in_sizes, int n_in,
                              void* d_out, int out_size, void* d_ws, size_t ws_size,
                              hipStream_t stream) {
    const int*   query = (const int*)d_in[0];
    const int*   doc   = (const int*)d_in[1];
    const float* emb   = (const float*)d_in[2];
    const float* w1    = (const float*)d_in[3];
    const float* b1    = (const float*)d_in[4];
    const float* w2    = (const float*)d_in[5];
    const float* b2    = (const float*)d_in[6];
    const float* w3    = (const float*)d_in[7];
    const float* b3    = (const float*)d_in[8];
    float* outp = (float*)d_out;

    const int V = in_sizes[2] / D_;
    const size_t need = (size_t)V * D_ * sizeof(unsigned short);

    if (ws_size >= need) {
        unsigned short* tbl = (unsigned short*)d_ws;
        norm_table_kernel<<<dim3((V + 15) / 16), dim3(256), 0, stream>>>(emb, tbl, V);
        knrm_mfma_kernel<<<dim3(B_), dim3(512), 0, stream>>>(query, doc, tbl,
                                                             w1, b1, w2, b2, w3, b3, outp);
    } else {
        knrm_kernel<<<dim3(B_), dim3(512), 0, stream>>>(query, doc, emb,
                                                        w1, b1, w2, b2, w3, b3, outp);
    }
}

// Round 11
// 58.095 us; speedup vs baseline: 1.8706x; 1.0050x over previous
//
#include <hip/hip_runtime.h>
#include <math.h>

#define B_   512
#define W_   30
#define R_   512
#define D_   128
#define NK_  21
#define QSTRIDE 132   // fp32 fallback kernel: 128 + 4 pad

typedef __attribute__((ext_vector_type(8))) short  bf16x8;
typedef __attribute__((ext_vector_type(4))) float  f32x4;
typedef __attribute__((ext_vector_type(2))) float  f32x2;

__device__ __forceinline__ unsigned short f2bf(float f) {
    union { float f; unsigned int u; } v; v.f = f;
    unsigned int u = v.u;
    return (unsigned short)((u + 0x7fffu + ((u >> 16) & 1u)) >> 16);  // RTNE
}

__device__ __forceinline__ float fast_exp2(float x) {
#if __has_builtin(__builtin_amdgcn_exp2f)
    return __builtin_amdgcn_exp2f(x);
#else
    float r; asm volatile("v_exp_f32 %0, %1" : "=v"(r) : "v"(x)); return r;
#endif
}

// ---------------- kernel 1: normalize emb table -> bf16 table in d_ws ----------------
__global__ __launch_bounds__(256) void norm_table_kernel(
    const float* __restrict__ emb, unsigned short* __restrict__ tbl, int V)
{
    const int t   = threadIdx.x;
    const int row = blockIdx.x * 16 + (t >> 4);
    const int j   = t & 15;                      // 16 lanes per row, 8 f32 each
    if (row >= V) return;

    const float4* src = (const float4*)(emb + (size_t)row * D_ + j * 8);
    float4 a = src[0], b = src[1];
    float ss = a.x*a.x + a.y*a.y + a.z*a.z + a.w*a.w
             + b.x*b.x + b.y*b.y + b.z*b.z + b.w*b.w;
    #pragma unroll
    for (int off = 8; off >= 1; off >>= 1) ss += __shfl_xor(ss, off, 16);
    const float inv = 1.0f / fmaxf(sqrtf(ss), 1e-12f);

    unsigned short o[8];
    o[0] = f2bf(a.x*inv); o[1] = f2bf(a.y*inv); o[2] = f2bf(a.z*inv); o[3] = f2bf(a.w*inv);
    o[4] = f2bf(b.x*inv); o[5] = f2bf(b.y*inv); o[6] = f2bf(b.z*inv); o[7] = f2bf(b.w*inv);
    *(uint4*)(tbl + (size_t)row * D_ + j * 8) = *(const uint4*)o;
}

// ---------------- kernel 2: MFMA cosine matrix + bins + MLP (pipelined) ----------------
#define QROWS 32
#define QST   136   // ushort stride per row (272 B): breaks 16-row same-bank pattern

__global__ __launch_bounds__(512) void knrm_mfma_kernel(
    const int* __restrict__ query, const int* __restrict__ doc,
    const unsigned short* __restrict__ tbl,   // [V][128] normalized bf16
    const float* __restrict__ w1, const float* __restrict__ b1,
    const float* __restrict__ w2, const float* __restrict__ b2,
    const float* __restrict__ w3, const float* __restrict__ b3,
    float* __restrict__ out)
{
    const int b    = blockIdx.x;
    const int tid  = threadIdx.x;
    const int lane = tid & 63;
    const int wid  = tid >> 6;          // 8 waves
    const int l15  = lane & 15;
    const int lhi  = lane >> 4;

    __shared__ unsigned short qlds[QROWS * QST];
    __shared__ float wred[8][NK_];
    __shared__ float klds[NK_];
    __shared__ float h1lds[128];

    // ---- all doc indices for this wave's 64 rows, up front ----
    int di[4];
    #pragma unroll
    for (int tr = 0; tr < 4; ++tr)
        di[tr] = doc[b * R_ + wid * 64 + tr * 16 + l15];

    // ---- issue A-gathers for tr=0 immediately (overlap with q staging below) ----
    bf16x8 acur[4], anxt[4];
    {
        const unsigned short* base = tbl + (size_t)di[0] * D_ + lhi * 8;
        #pragma unroll
        for (int kk = 0; kk < 4; ++kk) acur[kk] = *(const bf16x8*)(base + kk * 32);
    }

    // ---- gather pre-normalized q-hat rows (bf16) into LDS; pad rows 30,31 with 0 ----
    {
        int w = tid >> 4, j = tid & 15;
        uint4 v = make_uint4(0, 0, 0, 0);
        if (w < W_) {
            int qi = query[b * W_ + w];
            v = *(const uint4*)(tbl + (size_t)qi * D_ + j * 8);
        }
        *(uint4*)(&qlds[w * QST + j * 8]) = v;
    }
    __syncthreads();

    // ---- B fragments: q-hat rows, 2 col-tiles x 4 k-steps ----
    bf16x8 bq[2][4];
    #pragma unroll
    for (int tc = 0; tc < 2; ++tc)
        #pragma unroll
        for (int kk = 0; kk < 4; ++kk)
            bq[tc][kk] = *(const bf16x8*)&qlds[(tc * 16 + l15) * QST + kk * 32 + lhi * 8];

    // ---- bin constants ----
    const float CW = -72.134752f;     // -0.5/0.1^2 * log2(e)
    const float CE = -721347.52f;     // exact bin, sigma=0.001

    f32x2 kacc2[NK_];
    #pragma unroll
    for (int i = 0; i < NK_; ++i) kacc2[i] = (f32x2)0.0f;

    // ---- pipelined main loop: prefetch(tr+1) || MFMA(tr) || bins(tr) ----
    #pragma unroll
    for (int tr = 0; tr < 4; ++tr) {
        if (tr < 3) {   // prefetch next 16-row group's A fragments
            const unsigned short* base = tbl + (size_t)di[tr + 1] * D_ + lhi * 8;
            #pragma unroll
            for (int kk = 0; kk < 4; ++kk) anxt[kk] = *(const bf16x8*)(base + kk * 32);
        }

        f32x4 acc0 = (f32x4)0.0f, acc1 = (f32x4)0.0f;
        #pragma unroll
        for (int kk = 0; kk < 4; ++kk) {
            acc0 = __builtin_amdgcn_mfma_f32_16x16x32_bf16(acur[kk], bq[0][kk], acc0, 0, 0, 0);
            acc1 = __builtin_amdgcn_mfma_f32_16x16x32_bf16(acur[kk], bq[1][kk], acc1, 0, 0, 0);
        }

        // bins for this 16-row group: ~1.3K cycles of VALU/trans, hides the prefetch
        #pragma unroll
        for (int p = 0; p < 4; ++p) {
            f32x2 mm;
            mm.x = acc0[p];                              // w = l15 (always valid)
            mm.y = (l15 < 14) ? acc1[p] : 3.0f;          // w = 16+l15, mask w>=30
            f32x2 t = mm + 0.95f;                        // m - mu0, mu0 = -0.95
            f32x2 e = (CW * t) * t;
            f32x2 d = 14.4269504f * t - 0.72134752f;
            #pragma unroll
            for (int i = 0; i < 20; ++i) {
                f32x2 T;
                T.x = fast_exp2(e.x);
                T.y = fast_exp2(e.y);
                kacc2[i] += T;
                e += d;
                d += -1.44269504f;
            }
            f32x2 y = mm - 1.0f;
            f32x2 a20 = (CE * y) * y;
            f32x2 T20;
            T20.x = fast_exp2(a20.x);
            T20.y = fast_exp2(a20.y);
            kacc2[20] += T20;
        }

        if (tr < 3) {
            #pragma unroll
            for (int kk = 0; kk < 4; ++kk) acur[kk] = anxt[kk];
        }
    }

    // ---- block reduction of 21 accumulators ----
    #pragma unroll
    for (int i = 0; i < NK_; ++i) {
        float v = kacc2[i].x + kacc2[i].y;
        #pragma unroll
        for (int off = 32; off >= 1; off >>= 1) v += __shfl_xor(v, off, 64);
        if (lane == 0) wred[wid][i] = v;
    }
    __syncthreads();
    if (tid < NK_) {
        float s = 0.f;
        #pragma unroll
        for (int ww = 0; ww < 8; ++ww) s += wred[ww][tid];
        klds[tid] = log1pf(s);
    }
    __syncthreads();

    // ---- MLP 21 -> 128 -> 64 -> 1 ----
    if (tid < 128) {
        float h = b1[tid];
        #pragma unroll
        for (int i = 0; i < NK_; ++i) h = fmaf(klds[i], w1[i * 128 + tid], h);
        h1lds[tid] = fmaxf(h, 0.f);
    }
    __syncthreads();
    if (tid < 64) {
        float h = b2[tid];
        #pragma unroll 8
        for (int i = 0; i < 128; ++i) h = fmaf(h1lds[i], w2[i * 64 + tid], h);
        float p = fmaxf(h, 0.f) * w3[tid];
        #pragma unroll
        for (int off = 32; off >= 1; off >>= 1) p += __shfl_xor(p, off, 64);
        if (tid == 0) out[b] = p + b3[0];
    }
}

// ---------------- fp32 fallback (round-5 kernel, exact) ----------------
__global__ __launch_bounds__(512) void knrm_kernel(
    const int* __restrict__ query, const int* __restrict__ doc,
    const float* __restrict__ emb,
    const float* __restrict__ w1, const float* __restrict__ b1,
    const float* __restrict__ w2, const float* __restrict__ b2,
    const float* __restrict__ w3, const float* __restrict__ b3,
    float* __restrict__ out)
{
    const int b   = blockIdx.x;
    const int tid = threadIdx.x;

    __shared__ float qs[W_ * QSTRIDE];
    __shared__ float qinv[W_];
    __shared__ float wred[8][NK_];
    __shared__ float klds[NK_];
    __shared__ float h1lds[128];

    for (int idx = tid; idx < W_ * D_; idx += 512) {
        int w = idx >> 7, k = idx & 127;
        int qi = query[b * W_ + w];
        qs[w * QSTRIDE + k] = emb[(size_t)qi * D_ + k];
    }
    __syncthreads();

    if (tid < W_ * 16) {
        int row = tid >> 4, j = tid & 15;
        float ss = 0.f;
        #pragma unroll
        for (int k = 0; k < D_; k += 16) {
            float v = qs[row * QSTRIDE + k + j];
            ss = fmaf(v, v, ss);
        }
        #pragma unroll
        for (int off = 8; off >= 1; off >>= 1) ss += __shfl_xor(ss, off, 16);
        if (j == 0) qinv[row] = 1.0f / fmaxf(sqrtf(ss), 1e-12f);
    }
    __syncthreads();

    const int didx = doc[b * R_ + tid];
    const float4* __restrict__ drow = (const float4*)(emb + (size_t)didx * D_);

    float acc[W_];
    #pragma unroll
    for (int w = 0; w < W_; ++w) acc[w] = 0.f;
    float nsq = 0.f;

    float4 dv = drow[0];
    for (int c = 0; c < D_ / 4; ++c) {
        float4 dnx = drow[(c + 1) & 31];
        nsq = fmaf(dv.x, dv.x, fmaf(dv.y, dv.y, fmaf(dv.z, dv.z, fmaf(dv.w, dv.w, nsq))));
        const float* qc = qs + c * 4;
        #pragma unroll
        for (int w = 0; w < W_; ++w) {
            float4 qv = *(const float4*)(qc + w * QSTRIDE);
            acc[w] = fmaf(qv.x, dv.x, fmaf(qv.y, dv.y, fmaf(qv.z, dv.z, fmaf(qv.w, dv.w, acc[w]))));
        }
        dv = dnx;
    }
    const float invd = 1.0f / fmaxf(sqrtf(nsq), 1e-12f);

    const float CW = -72.134752f;
    const float CE = -721347.52f;
    float kacc[NK_];
    #pragma unroll
    for (int i = 0; i < NK_; ++i) kacc[i] = 0.f;

    #pragma unroll
    for (int w = 0; w < W_; ++w) {
        float m = acc[w] * qinv[w] * invd;
        #pragma unroll
        for (int i = 0; i < 20; ++i) {
            const float mu = (float)(1.0 / (NK_ - 1) + 2.0 * (double)i / (NK_ - 1) - 1.0);
            float t = m - mu;
            kacc[i] += exp2f(CW * t * t);
        }
        float y = m - 1.0f;
        kacc[20] += exp2f(CE * y * y);
    }

    const int wid = tid >> 6, lane = tid & 63;
    #pragma unroll
    for (int i = 0; i < NK_; ++i) {
        float v = kacc[i];
        #pragma unroll
        for (int off = 32; off >= 1; off >>= 1) v += __shfl_xor(v, off, 64);
        if (lane == 0) wred[wid][i] = v;
    }
    __syncthreads();
    if (tid < NK_) {
        float s = 0.f;
        #pragma unroll
        for (int ww = 0; ww < 8; ++ww) s += wred[ww][tid];
        klds[tid] = log1pf(s);
    }
    __syncthreads();

    if (tid < 128) {
        float h = b1[tid];
        #pragma unroll
        for (int i = 0; i < NK_; ++i) h = fmaf(klds[i], w1[i * 128 + tid], h);
        h1lds[tid] = fmaxf(h, 0.f);
    }
    __syncthreads();
    if (tid < 64) {
        float h = b2[tid];
        #pragma unroll 8
        for (int i = 0; i < 128; ++i) h = fmaf(h1lds[i], w2[i * 64 + tid], h);
        float p = fmaxf(h, 0.f) * w3[tid];
        #pragma unroll
        for (int off = 32; off >= 1; off >>= 1) p += __shfl_xor(p, off, 64);
        if (tid == 0) out[b] = p + b3[0];
    }
}

extern "C" void kernel_launch(void* const* d_in, const int* in_sizes, int n_in,
                              void* d_out, int out_size, void* d_ws, size_t ws_size,
                              hipStream_t stream) {
    const int*   query = (const int*)d_in[0];
    const int*   doc   = (const int*)d_in[1];
    const float* emb   = (const float*)d_in[2];
    const float* w1    = (const float*)d_in[3];
    const float* b1    = (const float*)d_in[4];
    const float* w2    = (const float*)d_in[5];
    const float* b2    = (const float*)d_in[6];
    const float* w3    = (const float*)d_in[7];
    const float* b3    = (const float*)d_in[8];
    float* outp = (float*)d_out;

    const int V = in_sizes[2] / D_;
    const size_t need = (size_t)V * D_ * sizeof(unsigned short);

    if (ws_size >= need) {
        unsigned short* tbl = (unsigned short*)d_ws;
        norm_table_kernel<<<dim3((V + 15) / 16), dim3(256), 0, stream>>>(emb, tbl, V);
        knrm_mfma_kernel<<<dim3(B_), dim3(512), 0, stream>>>(query, doc, tbl,
                                                             w1, b1, w2, b2, w3, b3, outp);
    } else {
        knrm_kernel<<<dim3(B_), dim3(512), 0, stream>>>(query, doc, emb,
                                                        w1, b1, w2, b2, w3, b3, outp);
    }
}

// Round 12
// 50.748 us; speedup vs baseline: 2.1415x; 1.1448x over previous
//
#include <hip/hip_runtime.h>
#include <math.h>

#define B_   512
#define W_   30
#define R_   512
#define D_   128
#define NK_  21
#define QSTRIDE 132   // fp32 fallback kernel: 128 + 4 pad

typedef __attribute__((ext_vector_type(8))) short  bf16x8;
typedef __attribute__((ext_vector_type(4))) float  f32x4;
typedef __attribute__((ext_vector_type(2))) float  f32x2;
typedef unsigned int u32;

__device__ __forceinline__ unsigned short f2bf(float f) {
    union { float f; unsigned int u; } v; v.f = f;
    unsigned int u = v.u;
    return (unsigned short)((u + 0x7fffu + ((u >> 16) & 1u)) >> 16);  // RTNE
}

__device__ __forceinline__ float fast_exp2(float x) {
#if __has_builtin(__builtin_amdgcn_exp2f)
    return __builtin_amdgcn_exp2f(x);
#else
    float r; asm volatile("v_exp_f32 %0, %1" : "=v"(r) : "v"(x)); return r;
#endif
}

// async global->LDS, 16B per lane, LDS dest = uniform base + lane*16 (HW rule)
__device__ __forceinline__ void gload_lds16(const void* g, void* l) {
    __builtin_amdgcn_global_load_lds(
        (const __attribute__((address_space(1))) u32*)g,
        (__attribute__((address_space(3))) u32*)l, 16, 0, 0);
}

// ---------------- kernel 1: normalize emb table -> bf16 table in d_ws ----------------
__global__ __launch_bounds__(256) void norm_table_kernel(
    const float* __restrict__ emb, unsigned short* __restrict__ tbl, int V)
{
    const int t   = threadIdx.x;
    const int row = blockIdx.x * 16 + (t >> 4);
    const int j   = t & 15;                      // 16 lanes per row, 8 f32 each
    if (row >= V) return;

    const float4* src = (const float4*)(emb + (size_t)row * D_ + j * 8);
    float4 a = src[0], b = src[1];
    float ss = a.x*a.x + a.y*a.y + a.z*a.z + a.w*a.w
             + b.x*b.x + b.y*b.y + b.z*b.z + b.w*b.w;
    #pragma unroll
    for (int off = 8; off >= 1; off >>= 1) ss += __shfl_xor(ss, off, 16);
    const float inv = 1.0f / fmaxf(sqrtf(ss), 1e-12f);

    unsigned short o[8];
    o[0] = f2bf(a.x*inv); o[1] = f2bf(a.y*inv); o[2] = f2bf(a.z*inv); o[3] = f2bf(a.w*inv);
    o[4] = f2bf(b.x*inv); o[5] = f2bf(b.y*inv); o[6] = f2bf(b.z*inv); o[7] = f2bf(b.w*inv);
    *(uint4*)(tbl + (size_t)row * D_ + j * 8) = *(const uint4*)o;
}

// ---------------- kernel 2: MFMA + bins + MLP, LDS-staged gathers ----------------
#define QROWS 32
#define QST   136   // ushort stride per row (272 B)

__global__ __launch_bounds__(512) void knrm_mfma_kernel(
    const int* __restrict__ query, const int* __restrict__ doc,
    const unsigned short* __restrict__ tbl,   // [V][128] normalized bf16
    const float* __restrict__ w1, const float* __restrict__ b1,
    const float* __restrict__ w2, const float* __restrict__ b2,
    const float* __restrict__ w3, const float* __restrict__ b3,
    float* __restrict__ out)
{
    const int b    = blockIdx.x;
    const int tid  = threadIdx.x;
    const int lane = tid & 63;
    const int wid  = tid >> 6;          // 8 waves
    const int l15  = lane & 15;
    const int lhi  = lane >> 4;

    __shared__ unsigned short qlds[QROWS * QST];          // 8704 B
    __shared__ unsigned short astage[8 * 2 * 2048];       // 8 waves x 2 bufs x 4KB = 64KB
    __shared__ float wred[8][NK_];
    __shared__ float klds[NK_];
    __shared__ float h1lds[128];

    // ---- doc indices for this wave's 64 rows (per-lane: row = tr*16 + l15) ----
    int di0 = doc[b * R_ + wid * 64 +  0 + l15];
    int di1 = doc[b * R_ + wid * 64 + 16 + l15];
    int di2 = doc[b * R_ + wid * 64 + 32 + l15];
    int di3 = doc[b * R_ + wid * 64 + 48 + l15];

    unsigned short* slice0 = &astage[wid * 4096];          // buf0 (4KB)
    unsigned short* slice1 = &astage[wid * 4096 + 2048];   // buf1 (4KB)

    // stage one 16-row group: 4 x global_load_lds, LDS[j][lane] <- row di[l15], 16B chunk (lhi,j)
    #define STAGE(dif, sl)                                                     \
        {                                                                      \
            const unsigned short* g = tbl + (size_t)(dif) * D_ + lhi * 8;      \
            _Pragma("unroll")                                                  \
            for (int j = 0; j < 4; ++j)                                        \
                gload_lds16(g + j * 32, (sl) + j * 512);                       \
        }

    // ---- prologue: S0,S1 in flight; their latency hides under q-staging + barrier ----
    STAGE(di0, slice0);
    STAGE(di1, slice1);

    // ---- gather pre-normalized q-hat rows (bf16) into LDS; pad rows 30,31 with 0 ----
    {
        int w = tid >> 4, j = tid & 15;
        uint4 v = make_uint4(0, 0, 0, 0);
        if (w < W_) {
            int qi = query[b * W_ + w];
            v = *(const uint4*)(tbl + (size_t)qi * D_ + j * 8);
        }
        *(uint4*)(&qlds[w * QST + j * 8]) = v;
    }
    __syncthreads();   // drains vmcnt: S0,S1 complete here too

    // ---- B fragments: q-hat rows, 2 col-tiles x 4 k-steps ----
    bf16x8 bq[2][4];
    #pragma unroll
    for (int tc = 0; tc < 2; ++tc)
        #pragma unroll
        for (int kk = 0; kk < 4; ++kk)
            bq[tc][kk] = *(const bf16x8*)&qlds[(tc * 16 + l15) * QST + kk * 32 + lhi * 8];

    const float CW = -72.134752f;     // -0.5/0.1^2 * log2(e)
    const float CE = -721347.52f;     // exact bin, sigma=0.001

    f32x2 kacc2[NK_];
    #pragma unroll
    for (int i = 0; i < NK_; ++i) kacc2[i] = (f32x2)0.0f;

    // per-group: ds_read frags -> MFMA -> (re-stage buf) -> bins
    #define MFMA_GROUP(sl, acc0, acc1)                                         \
        f32x4 acc0 = (f32x4)0.0f, acc1 = (f32x4)0.0f;                          \
        {                                                                      \
            _Pragma("unroll")                                                  \
            for (int kk = 0; kk < 4; ++kk) {                                   \
                bf16x8 a = *(const bf16x8*)((sl) + kk * 512 + lane * 8);       \
                acc0 = __builtin_amdgcn_mfma_f32_16x16x32_bf16(a, bq[0][kk], acc0, 0, 0, 0); \
                acc1 = __builtin_amdgcn_mfma_f32_16x16x32_bf16(a, bq[1][kk], acc1, 0, 0, 0); \
            }                                                                  \
        }

    #define BINS(acc0, acc1)                                                   \
        {                                                                      \
            _Pragma("unroll")                                                  \
            for (int p = 0; p < 4; ++p) {                                      \
                f32x2 mm;                                                      \
                mm.x = acc0[p];                                                \
                mm.y = (l15 < 14) ? acc1[p] : 3.0f;                            \
                f32x2 t = mm + 0.95f;                                          \
                f32x2 e = (CW * t) * t;                                        \
                f32x2 d = 14.4269504f * t - 0.72134752f;                       \
                _Pragma("unroll")                                              \
                for (int i = 0; i < 20; ++i) {                                 \
                    f32x2 T;                                                   \
                    T.x = fast_exp2(e.x);                                      \
                    T.y = fast_exp2(e.y);                                      \
                    kacc2[i] += T;                                             \
                    e += d;                                                    \
                    d += -1.44269504f;                                         \
                }                                                              \
                f32x2 y = mm - 1.0f;                                           \
                f32x2 a20 = (CE * y) * y;                                      \
                f32x2 T20;                                                     \
                T20.x = fast_exp2(a20.x);                                      \
                T20.y = fast_exp2(a20.y);                                      \
                kacc2[20] += T20;                                              \
            }                                                                  \
        }

    // ---- tr0: buf0 ready (barrier-drained). MFMA, then refill buf0 with S2. ----
    {
        MFMA_GROUP(slice0, a0, a1)           // lgkm waits auto-inserted for ds_read->MFMA
        STAGE(di2, slice0);                  // refill after MFMAs consumed the reads
        BINS(a0, a1)
    }
    // ---- tr1: buf1 ready. MFMA, refill buf1 with S3. ----
    {
        MFMA_GROUP(slice1, a0, a1)
        STAGE(di3, slice1);
        BINS(a0, a1)
    }
    // ---- tr2: need S2 (oldest 4 of 8 outstanding) ----
    {
        asm volatile("s_waitcnt vmcnt(4)" ::: "memory");
        __builtin_amdgcn_sched_barrier(0);
        MFMA_GROUP(slice0, a0, a1)
        BINS(a0, a1)
    }
    // ---- tr3: need S3 (drain) ----
    {
        asm volatile("s_waitcnt vmcnt(0)" ::: "memory");
        __builtin_amdgcn_sched_barrier(0);
        MFMA_GROUP(slice1, a0, a1)
        BINS(a0, a1)
    }

    // ---- block reduction of 21 accumulators ----
    #pragma unroll
    for (int i = 0; i < NK_; ++i) {
        float v = kacc2[i].x + kacc2[i].y;
        #pragma unroll
        for (int off = 32; off >= 1; off >>= 1) v += __shfl_xor(v, off, 64);
        if (lane == 0) wred[wid][i] = v;
    }
    __syncthreads();
    if (tid < NK_) {
        float s = 0.f;
        #pragma unroll
        for (int ww = 0; ww < 8; ++ww) s += wred[ww][tid];
        klds[tid] = log1pf(s);
    }
    __syncthreads();

    // ---- MLP 21 -> 128 -> 64 -> 1 ----
    if (tid < 128) {
        float h = b1[tid];
        #pragma unroll
        for (int i = 0; i < NK_; ++i) h = fmaf(klds[i], w1[i * 128 + tid], h);
        h1lds[tid] = fmaxf(h, 0.f);
    }
    __syncthreads();
    if (tid < 64) {
        float h = b2[tid];
        #pragma unroll 8
        for (int i = 0; i < 128; ++i) h = fmaf(h1lds[i], w2[i * 64 + tid], h);
        float p = fmaxf(h, 0.f) * w3[tid];
        #pragma unroll
        for (int off = 32; off >= 1; off >>= 1) p += __shfl_xor(p, off, 64);
        if (tid == 0) out[b] = p + b3[0];
    }
    #undef STAGE
    #undef MFMA_GROUP
    #undef BINS
}

// ---------------- fp32 fallback (round-5 kernel, exact) ----------------
__global__ __launch_bounds__(512) void knrm_kernel(
    const int* __restrict__ query, const int* __restrict__ doc,
    const float* __restrict__ emb,
    const float* __restrict__ w1, const float* __restrict__ b1,
    const float* __restrict__ w2, const float* __restrict__ b2,
    const float* __restrict__ w3, const float* __restrict__ b3,
    float* __restrict__ out)
{
    const int b   = blockIdx.x;
    const int tid = threadIdx.x;

    __shared__ float qs[W_ * QSTRIDE];
    __shared__ float qinv[W_];
    __shared__ float wred[8][NK_];
    __shared__ float klds[NK_];
    __shared__ float h1lds[128];

    for (int idx = tid; idx < W_ * D_; idx += 512) {
        int w = idx >> 7, k = idx & 127;
        int qi = query[b * W_ + w];
        qs[w * QSTRIDE + k] = emb[(size_t)qi * D_ + k];
    }
    __syncthreads();

    if (tid < W_ * 16) {
        int row = tid >> 4, j = tid & 15;
        float ss = 0.f;
        #pragma unroll
        for (int k = 0; k < D_; k += 16) {
            float v = qs[row * QSTRIDE + k + j];
            ss = fmaf(v, v, ss);
        }
        #pragma unroll
        for (int off = 8; off >= 1; off >>= 1) ss += __shfl_xor(ss, off, 16);
        if (j == 0) qinv[row] = 1.0f / fmaxf(sqrtf(ss), 1e-12f);
    }
    __syncthreads();

    const int didx = doc[b * R_ + tid];
    const float4* __restrict__ drow = (const float4*)(emb + (size_t)didx * D_);

    float acc[W_];
    #pragma unroll
    for (int w = 0; w < W_; ++w) acc[w] = 0.f;
    float nsq = 0.f;

    float4 dv = drow[0];
    for (int c = 0; c < D_ / 4; ++c) {
        float4 dnx = drow[(c + 1) & 31];
        nsq = fmaf(dv.x, dv.x, fmaf(dv.y, dv.y, fmaf(dv.z, dv.z, fmaf(dv.w, dv.w, nsq))));
        const float* qc = qs + c * 4;
        #pragma unroll
        for (int w = 0; w < W_; ++w) {
            float4 qv = *(const float4*)(qc + w * QSTRIDE);
            acc[w] = fmaf(qv.x, dv.x, fmaf(qv.y, dv.y, fmaf(qv.z, dv.z, fmaf(qv.w, dv.w, acc[w]))));
        }
        dv = dnx;
    }
    const float invd = 1.0f / fmaxf(sqrtf(nsq), 1e-12f);

    const float CW = -72.134752f;
    const float CE = -721347.52f;
    float kacc[NK_];
    #pragma unroll
    for (int i = 0; i < NK_; ++i) kacc[i] = 0.f;

    #pragma unroll
    for (int w = 0; w < W_; ++w) {
        float m = acc[w] * qinv[w] * invd;
        #pragma unroll
        for (int i = 0; i < 20; ++i) {
            const float mu = (float)(1.0 / (NK_ - 1) + 2.0 * (double)i / (NK_ - 1) - 1.0);
            float t = m - mu;
            kacc[i] += exp2f(CW * t * t);
        }
        float y = m - 1.0f;
        kacc[20] += exp2f(CE * y * y);
    }

    const int wid = tid >> 6, lane = tid & 63;
    #pragma unroll
    for (int i = 0; i < NK_; ++i) {
        float v = kacc[i];
        #pragma unroll
        for (int off = 32; off >= 1; off >>= 1) v += __shfl_xor(v, off, 64);
        if (lane == 0) wred[wid][i] = v;
    }
    __syncthreads();
    if (tid < NK_) {
        float s = 0.f;
        #pragma unroll
        for (int ww = 0; ww < 8; ++ww) s += wred[ww][tid];
        klds[tid] = log1pf(s);
    }
    __syncthreads();

    if (tid < 128) {
        float h = b1[tid];
        #pragma unroll
        for (int i = 0; i < NK_; ++i) h = fmaf(klds[i], w1[i * 128 + tid], h);
        h1lds[tid] = fmaxf(h, 0.f);
    }
    __syncthreads();
    if (tid < 64) {
        float h = b2[tid];
        #pragma unroll 8
        for (int i = 0; i < 128; ++i) h = fmaf(h1lds[i], w2[i * 64 + tid], h);
        float p = fmaxf(h, 0.f) * w3[tid];
        #pragma unroll
        for (int off = 32; off >= 1; off >>= 1) p += __shfl_xor(p, off, 64);
        if (tid == 0) out[b] = p + b3[0];
    }
}

extern "C" void kernel_launch(void* const* d_in, const int* in_sizes, int n_in,
                              void* d_out, int out_size, void* d_ws, size_t ws_size,
                              hipStream_t stream) {
    const int*   query = (const int*)d_in[0];
    const int*   doc   = (const int*)d_in[1];
    const float* emb   = (const float*)d_in[2];
    const float* w1    = (const float*)d_in[3];
    const float* b1    = (const float*)d_in[4];
    const float* w2    = (const float*)d_in[5];
    const float* b2    = (const float*)d_in[6];
    const float* w3    = (const float*)d_in[7];
    const float* b3    = (const float*)d_in[8];
    float* outp = (float*)d_out;

    const int V = in_sizes[2] / D_;
    const size_t need = (size_t)V * D_ * sizeof(unsigned short);

    if (ws_size >= need) {
        unsigned short* tbl = (unsigned short*)d_ws;
        norm_table_kernel<<<dim3((V + 15) / 16), dim3(256), 0, stream>>>(emb, tbl, V);
        knrm_mfma_kernel<<<dim3(B_), dim3(512), 0, stream>>>(query, doc, tbl,
                                                             w1, b1, w2, b2, w3, b3, outp);
    } else {
        knrm_kernel<<<dim3(B_), dim3(512), 0, stream>>>(query, doc, emb,
                                                        w1, b1, w2, b2, w3, b3, outp);
    }
}